// Round 1
// baseline (136.281 us; speedup 1.0000x reference)
//
#include <hip/hip_runtime.h>
#include <math.h>

#define B_ 4
#define C_ 32
#define D_ 16
#define H_ 128
#define W_ 128
#define HW_ (H_*W_)
#define SP_ (D_*HW_)

__device__ __forceinline__ int refl(int i, int n) {
    i = (i < 0) ? -i : i;
    i = (i >= n) ? (2*n - 2 - i) : i;
    return i;
}

// Pass 0: combined stencil Wc[ci][od][oh][ow] (2x7x7x5), offsets od,oh in -3..3 (idx 0..6), ow in -2..2 (idx 0..4)
__global__ void prep_weights_kernel(const float* __restrict__ w1,
                                    const float* __restrict__ w2,
                                    const float* __restrict__ w3,
                                    const float* __restrict__ wf,
                                    float* __restrict__ Wc) {
    int t = blockIdx.x * blockDim.x + threadIdx.x;
    if (t >= 2*7*7*5) return;
    int ow = t % 5;
    int oh = (t / 5) % 7;
    int od = (t / 35) % 7;
    int ci = t / 245;
    float v = wf[0] * w1[((ci*7+od)*7+oh)*5+ow];
    if (od>=1 && od<=5 && oh>=1 && oh<=5 && ow>=1 && ow<=3)
        v = fmaf(wf[1], w2[((ci*5+(od-1))*5+(oh-1))*3+(ow-1)], v);
    if (od>=2 && od<=4 && oh>=2 && oh<=4 && ow==2)
        v = fmaf(wf[2], w3[(ci*3+(od-2))*3+(oh-2)], v);
    Wc[t] = v;
}

// Pass 1: channel pool -> s[b][0]=mean, s[b][1]=max, layout [B][2][D][H][W]
__global__ __launch_bounds__(256) void pool_kernel(const float* __restrict__ x,
                                                   float* __restrict__ s) {
    int t = blockIdx.x * blockDim.x + threadIdx.x;
    if (t >= B_*D_*H_*(W_/4)) return;
    int w4 = (t % (W_/4)) * 4;
    int rest = t / (W_/4);
    int h = rest % H_;
    int bd = rest / H_;
    int d = bd % D_;
    int b = bd / D_;
    const float* xp = x + (b*C_*D_ + d)*HW_ + h*W_ + w4;
    float4 v = *(const float4*)xp;
    float sx=v.x, sy=v.y, sz=v.z, sw=v.w;
    float mx=v.x, my=v.y, mz=v.z, mw=v.w;
    #pragma unroll 4
    for (int c = 1; c < C_; ++c) {
        float4 u = *(const float4*)(xp + c*SP_);
        sx+=u.x; sy+=u.y; sz+=u.z; sw+=u.w;
        mx=fmaxf(mx,u.x); my=fmaxf(my,u.y); mz=fmaxf(mz,u.z); mw=fmaxf(mw,u.w);
    }
    const float inv = 1.0f/32.0f;
    float* sm = s + ((b*2+0)*D_ + d)*HW_ + h*W_ + w4;
    float* sM = s + ((b*2+1)*D_ + d)*HW_ + h*W_ + w4;
    float4 a; a.x=sx*inv; a.y=sy*inv; a.z=sz*inv; a.w=sw*inv;
    float4 m; m.x=mx; m.y=my; m.z=mz; m.w=mw;
    *(float4*)sm = a;
    *(float4*)sM = m;
}

// Pass 2: combined 2x7x7x5 stencil over s + sigmoid + multiply into x.
// Thread tile: 2 consecutive d, 4 consecutive w (float4-aligned), one h.
// Block: 256 threads = 32 w-tiles (full W) x 8 h. Grid: B * (D/2) * (H/8) = 512.
__global__ __launch_bounds__(256) void spatial_att_kernel(
        const float* __restrict__ x,
        const float* __restrict__ s,
        const float* __restrict__ Wc,
        float* __restrict__ out) {
    int bid = blockIdx.x;
    int ht = bid & 15;
    int dt = (bid >> 4) & 7;
    int b  = bid >> 7;
    int t = threadIdx.x;
    int w0 = (t & 31) * 4;
    int h0 = ht * 8 + (t >> 5);
    int d0 = dt * 2;

    float acc0[4] = {0.f,0.f,0.f,0.f};
    float acc1[4] = {0.f,0.f,0.f,0.f};

    int wj[8];
    #pragma unroll
    for (int j = 0; j < 8; ++j) wj[j] = refl(w0 - 2 + j, W_);

    for (int ci = 0; ci < 2; ++ci) {
        const float* sc = s + (b*2 + ci)*SP_;
        const float* wcbase = Wc + ci*245;
        for (int oh = 0; oh < 7; ++oh) {
            const float* sh = sc + refl(h0 + oh - 3, H_)*W_;
            const float* wbase = wcbase + oh*5;   // + od*35 + ow
            #pragma unroll
            for (int k = -3; k <= 4; ++k) {
                const float* row = sh + refl(d0 + k, D_)*HW_;
                float v[8];
                #pragma unroll
                for (int j = 0; j < 8; ++j) v[j] = row[wj[j]];
                // output d0 (di=0): od = k+3 valid for k <= 3
                if (k <= 3) {
                    const float* wp = wbase + (k+3)*35;
                    #pragma unroll
                    for (int ow = 0; ow < 5; ++ow) {
                        float wgt = wp[ow];
                        #pragma unroll
                        for (int wi = 0; wi < 4; ++wi)
                            acc0[wi] = fmaf(wgt, v[wi+ow], acc0[wi]);
                    }
                }
                // output d0+1 (di=1): od = k+2 valid for k >= -2
                if (k >= -2) {
                    const float* wp = wbase + (k+2)*35;
                    #pragma unroll
                    for (int ow = 0; ow < 5; ++ow) {
                        float wgt = wp[ow];
                        #pragma unroll
                        for (int wi = 0; wi < 4; ++wi)
                            acc1[wi] = fmaf(wgt, v[wi+ow], acc1[wi]);
                    }
                }
            }
        }
    }

    float sg0[4], sg1[4];
    #pragma unroll
    for (int wi = 0; wi < 4; ++wi) {
        sg0[wi] = 1.0f/(1.0f + expf(-acc0[wi]));
        sg1[wi] = 1.0f/(1.0f + expf(-acc1[wi]));
    }

    int obase = (b*C_*D_ + d0)*HW_ + h0*W_ + w0;
    for (int c = 0; c < C_; ++c) {
        int i0 = obase + c*SP_;
        float4 xv0 = *(const float4*)(x + i0);
        float4 xv1 = *(const float4*)(x + i0 + HW_);
        float4 o0; o0.x=xv0.x*sg0[0]; o0.y=xv0.y*sg0[1]; o0.z=xv0.z*sg0[2]; o0.w=xv0.w*sg0[3];
        float4 o1; o1.x=xv1.x*sg1[0]; o1.y=xv1.y*sg1[1]; o1.z=xv1.z*sg1[2]; o1.w=xv1.w*sg1[3];
        *(float4*)(out + i0) = o0;
        *(float4*)(out + i0 + HW_) = o1;
    }
}

extern "C" void kernel_launch(void* const* d_in, const int* in_sizes, int n_in,
                              void* d_out, int out_size, void* d_ws, size_t ws_size,
                              hipStream_t stream) {
    const float* x  = (const float*)d_in[0];
    const float* w1 = (const float*)d_in[1];
    const float* w2 = (const float*)d_in[2];
    const float* w3 = (const float*)d_in[3];
    const float* wf = (const float*)d_in[4];
    float* out = (float*)d_out;
    float* Wc = (float*)d_ws;            // 490 floats (rounded to 512)
    float* s  = (float*)d_ws + 512;      // [B][2][D][H][W] = 8 MB

    prep_weights_kernel<<<1, 512, 0, stream>>>(w1, w2, w3, wf, Wc);
    pool_kernel<<<(B_*D_*H_*(W_/4) + 255)/256, 256, 0, stream>>>(x, s);
    spatial_att_kernel<<<B_*(D_/2)*(H_/8), 256, 0, stream>>>(x, s, Wc, out);
}

// Round 3
// 88.571 us; speedup vs baseline: 1.5387x; 1.5387x over previous
//
#include <hip/hip_runtime.h>
#include <math.h>

#define B_ 4
#define C_ 32
#define D_ 16
#define H_ 128
#define W_ 128
#define HW_ (H_*W_)
#define SP_ (D_*HW_)

typedef float f32x4 __attribute__((ext_vector_type(4)));

__device__ __forceinline__ int refl(int i, int n) {
    i = (i < 0) ? -i : i;
    i = (i >= n) ? (2*n - 2 - i) : i;
    return i;
}

// Pass 0: combined stencil Wc[ci][od][oh][ow] (2x7x7x5)
__global__ void prep_weights_kernel(const float* __restrict__ w1,
                                    const float* __restrict__ w2,
                                    const float* __restrict__ w3,
                                    const float* __restrict__ wf,
                                    float* __restrict__ Wc) {
    int t = blockIdx.x * blockDim.x + threadIdx.x;
    if (t >= 2*7*7*5) return;
    int ow = t % 5;
    int oh = (t / 5) % 7;
    int od = (t / 35) % 7;
    int ci = t / 245;
    float v = wf[0] * w1[((ci*7+od)*7+oh)*5+ow];
    if (od>=1 && od<=5 && oh>=1 && oh<=5 && ow>=1 && ow<=3)
        v = fmaf(wf[1], w2[((ci*5+(od-1))*5+(oh-1))*3+(ow-1)], v);
    if (od>=2 && od<=4 && oh>=2 && oh<=4 && ow==2)
        v = fmaf(wf[2], w3[(ci*3+(od-2))*3+(oh-2)], v);
    Wc[t] = v;
}

// Pass 1: channel pool -> s[b][0]=mean, s[b][1]=max, layout [B][2][D][H][W]
__global__ __launch_bounds__(256) void pool_kernel(const float* __restrict__ x,
                                                   float* __restrict__ s) {
    int t = blockIdx.x * blockDim.x + threadIdx.x;
    if (t >= B_*D_*H_*(W_/4)) return;
    int w4 = (t % (W_/4)) * 4;
    int rest = t / (W_/4);
    int h = rest % H_;
    int bd = rest / H_;
    int d = bd % D_;
    int b = bd / D_;
    const float* xp = x + (b*C_*D_ + d)*HW_ + h*W_ + w4;
    f32x4 v = *(const f32x4*)xp;
    float sx=v.x, sy=v.y, sz=v.z, sw=v.w;
    float mx=v.x, my=v.y, mz=v.z, mw=v.w;
    #pragma unroll 4
    for (int c = 1; c < C_; ++c) {
        f32x4 u = *(const f32x4*)(xp + c*SP_);
        sx+=u.x; sy+=u.y; sz+=u.z; sw+=u.w;
        mx=fmaxf(mx,u.x); my=fmaxf(my,u.y); mz=fmaxf(mz,u.z); mw=fmaxf(mw,u.w);
    }
    const float inv = 1.0f/32.0f;
    float* sm = s + ((b*2+0)*D_ + d)*HW_ + h*W_ + w4;
    float* sM = s + ((b*2+1)*D_ + d)*HW_ + h*W_ + w4;
    f32x4 a; a.x=sx*inv; a.y=sy*inv; a.z=sz*inv; a.w=sw*inv;
    f32x4 m; m.x=mx; m.y=my; m.z=mz; m.w=mw;
    *(f32x4*)sm = a;
    *(f32x4*)sM = m;
}

// Pass 2: combined 2x7x7x5 stencil + sigmoid + multiply.
// Thread tile: 1 d, 1 h, 4 w (float4). Block 256 = 32 w-tiles (full W) x 8 h.
// Grid: B * D * (H/8) = 1024 blocks -> 16 waves/CU.
// Stencil row = one float4 load + 4 shuffles for the +/-2 w halo.
__global__ __launch_bounds__(256) void spatial_att_kernel(
        const float* __restrict__ x,
        const float* __restrict__ s,
        const float* __restrict__ Wc,
        float* __restrict__ out) {
    int bid = blockIdx.x;
    int ht = bid & 15;
    int d0 = (bid >> 4) & 15;
    int b  = bid >> 8;
    int t = threadIdx.x;
    int lane = t & 63;
    int w0 = (t & 31) * 4;
    int h0 = ht * 8 + (t >> 5);

    const bool le = (t & 31) == 0;    // w0 == 0   : left taps reflect into own float4
    const bool re = (t & 31) == 31;   // w0 == 124 : right taps reflect into own float4

    // block-uniform d-row offsets (scalar)
    int drow[7];
    #pragma unroll
    for (int od = 0; od < 7; ++od) drow[od] = refl(d0 + od - 3, D_) * HW_;

    float acc[4] = {0.f, 0.f, 0.f, 0.f};

    for (int ci = 0; ci < 2; ++ci) {
        const float* sc = s + (b*2 + ci)*SP_;
        const float* wcb_ci = Wc + ci*245;
        for (int oh = 0; oh < 7; ++oh) {
            const float* sh = sc + refl(h0 + oh - 3, H_)*W_ + w0;
            const float* wcb = wcb_ci + oh*5;
            #pragma unroll
            for (int od = 0; od < 7; ++od) {
                const f32x4 vv = *(const f32x4*)(sh + drow[od]);
                // halo via lane shuffles (same h-group; edge lanes use reflection)
                float lz = __shfl(vv.z, lane - 1);
                float lw = __shfl(vv.w, lane - 1);
                float rx = __shfl(vv.x, lane + 1);
                float ry = __shfl(vv.y, lane + 1);
                float v[8];
                v[0] = le ? vv.z : lz;   // w0-2  (refl(-2)=2)
                v[1] = le ? vv.y : lw;   // w0-1  (refl(-1)=1)
                v[2] = vv.x; v[3] = vv.y; v[4] = vv.z; v[5] = vv.w;
                v[6] = re ? vv.z : rx;   // w0+4  (refl(128)=126)
                v[7] = re ? vv.y : ry;   // w0+5  (refl(129)=125)
                const float* wp = wcb + od*35;
                #pragma unroll
                for (int ow = 0; ow < 5; ++ow) {
                    float wgt = wp[ow];
                    #pragma unroll
                    for (int wi = 0; wi < 4; ++wi)
                        acc[wi] = fmaf(wgt, v[wi+ow], acc[wi]);
                }
            }
        }
    }

    float sg[4];
    #pragma unroll
    for (int wi = 0; wi < 4; ++wi)
        sg[wi] = 1.0f/(1.0f + __expf(-acc[wi]));

    int obase = (b*C_*D_ + d0)*HW_ + h0*W_ + w0;
    #pragma unroll 4
    for (int c = 0; c < C_; ++c) {
        int i0 = obase + c*SP_;
        f32x4 xv = *(const f32x4*)(x + i0);
        f32x4 o; o.x=xv.x*sg[0]; o.y=xv.y*sg[1]; o.z=xv.z*sg[2]; o.w=xv.w*sg[3];
        __builtin_nontemporal_store(o, (f32x4*)(out + i0));
    }
}

extern "C" void kernel_launch(void* const* d_in, const int* in_sizes, int n_in,
                              void* d_out, int out_size, void* d_ws, size_t ws_size,
                              hipStream_t stream) {
    const float* x  = (const float*)d_in[0];
    const float* w1 = (const float*)d_in[1];
    const float* w2 = (const float*)d_in[2];
    const float* w3 = (const float*)d_in[3];
    const float* wf = (const float*)d_in[4];
    float* out = (float*)d_out;
    float* Wc = (float*)d_ws;            // 490 floats (rounded to 512)
    float* s  = (float*)d_ws + 512;      // [B][2][D][H][W] = 8 MB

    prep_weights_kernel<<<1, 512, 0, stream>>>(w1, w2, w3, wf, Wc);
    pool_kernel<<<(B_*D_*H_*(W_/4) + 255)/256, 256, 0, stream>>>(x, s);
    spatial_att_kernel<<<B_*D_*(H_/8), 256, 0, stream>>>(x, s, Wc, out);
}